// Round 3
// baseline (231.976 us; speedup 1.0000x reference)
//
#include <hip/hip_runtime.h>

typedef __attribute__((ext_vector_type(8)))  _Float16 half8;
typedef __attribute__((ext_vector_type(4)))  _Float16 half4;
typedef __attribute__((ext_vector_type(16))) float    f32x16;

#define G_LATENT 256
#define EMB      512
#define WFLAT    36864   // 64*64*3*3 per-sample weight count

// ---------------------------------------------------------------------------
// K1: hdn = relu(emb @ w1_w^T + b), emitted directly in f16 A-fragment order:
//   hdn16[(kb*64 + s + 32*h)*8 + e] = hdn[s][kb*16 + (e>>2)*8 + 4h + (e&3)]
// ---------------------------------------------------------------------------
__global__ __launch_bounds__(256) void k1_hdn(
    const float* __restrict__ emb, const float* __restrict__ w1w,
    const float* __restrict__ w1b, _Float16* __restrict__ hdn16)
{
    const int s = blockIdx.x;
    const int j = threadIdx.x;
    const float4* e4 = (const float4*)(emb + (size_t)s * EMB);
    const float4* w4 = (const float4*)(w1w + (size_t)j * EMB);
    float a0 = 0.f, a1 = 0.f;
#pragma unroll 8
    for (int k = 0; k < EMB / 4; k += 2) {
        float4 a = e4[k],     b = w4[k];
        float4 c = e4[k + 1], d = w4[k + 1];
        a0 += a.x * b.x + a.y * b.y + a.z * b.z + a.w * b.w;
        a1 += c.x * d.x + c.y * d.y + c.z * d.z + c.w * d.w;
    }
    const float acc = fmaxf(a0 + a1 + w1b[j], 0.f);
    const int kb = j >> 4;
    const int h  = (j >> 2) & 1;
    const int e  = (j & 3) + 4 * ((j >> 3) & 1);
    hdn16[(kb * 64 + s + 32 * h) * 8 + e] = (_Float16)acc;
}

// ---------------------------------------------------------------------------
// K2: weights = hdn @ w2_w^T + w2_b -> f16 MFMA A-fragments. 144 blocks.
// Same structure as R2 but no register double-buffer (VGPR pressure down).
// ---------------------------------------------------------------------------
__global__ __launch_bounds__(256) void k2_wfrag(
    const _Float16* __restrict__ hdn16, const float* __restrict__ w2w,
    const float* __restrict__ w2b, _Float16* __restrict__ wfrag)
{
    __shared__ __align__(16) _Float16 sm[8 * 256 * 8];  // 32 KiB

    const int b     = blockIdx.x;
    const int ihalf = b & 1;
    const int oct   = (b >> 1) & 1;
    const int kbc   = (b >> 2) & 3;
    const int khw   = b >> 4;          // 0..8

    const int t = threadIdx.x, lane = t & 63, wv = t >> 6;
    const int h = lane >> 5, l31 = lane & 31;

    const int oc31 = t & 31, icof = t >> 5;
    const size_t rrow = (size_t)(oct * 32 + oc31) * 576
                      + (size_t)(kbc * 16 + ihalf * 8 + icof) * 9 + khw;
    const float* wrow = w2w + rrow * G_LATENT;

    float bias[2];
#pragma unroll
    for (int ntl = 0; ntl < 2; ++ntl) {
        const int nt = wv * 2 + ntl;
        const size_t rc = (size_t)(oct * 32 + l31) * 576
                        + (size_t)(kbc * 16 + ihalf * 8 + nt) * 9 + khw;
        bias[ntl] = w2b[rc];
    }

    const f32x16 z16 = {0,0,0,0,0,0,0,0,0,0,0,0,0,0,0,0};
    f32x16 acc[2] = {z16, z16};
    const half8* __restrict__ hfr = (const half8*)hdn16;

#pragma unroll
    for (int kc = 0; kc < 4; ++kc) {
        __syncthreads();               // prev chunk's reads finished
        float4 ld[16];
        const float4* src = (const float4*)(wrow + kc * 64);
#pragma unroll
        for (int u = 0; u < 16; ++u) ld[u] = src[u];
#pragma unroll
        for (int kb16 = 0; kb16 < 4; ++kb16) {
#pragma unroll
            for (int hh = 0; hh < 2; ++hh) {
                const float4 lo = ld[kb16 * 4 + hh];
                const float4 hi = ld[kb16 * 4 + 2 + hh];
                half8 c;
                c[0] = (_Float16)lo.x; c[1] = (_Float16)lo.y;
                c[2] = (_Float16)lo.z; c[3] = (_Float16)lo.w;
                c[4] = (_Float16)hi.x; c[5] = (_Float16)hi.y;
                c[6] = (_Float16)hi.z; c[7] = (_Float16)hi.w;
                *(half8*)&sm[((kb16 * 2 + hh) * 256 + t) * 8] = c;
            }
        }
        __syncthreads();
#pragma unroll
        for (int kb16 = 0; kb16 < 4; ++kb16) {
            const half8 af = hfr[(kc * 4 + kb16) * 64 + lane];
#pragma unroll
            for (int ntl = 0; ntl < 2; ++ntl) {
                const int lr = (wv * 2 + ntl) * 32 + l31;
                const half8 bf = *(const half8*)&sm[((kb16 * 2 + h) * 256 + lr) * 8];
                acc[ntl] = __builtin_amdgcn_mfma_f32_32x32x16_f16(af, bf, acc[ntl], 0, 0, 0);
            }
        }
    }

    __syncthreads();
#pragma unroll
    for (int ntl = 0; ntl < 2; ++ntl) {
        const int nt    = wv * 2 + ntl;          // = ic_off
        const int lanep = l31 + 32 * (nt >> 2);
        const int elow  = nt & 3;
#pragma unroll
        for (int g = 0; g < 16; ++g) {
            const int srow = (g & 3) + 8 * (g >> 2) + 4 * h;  // sample
            sm[(srow * 64 + lanep) * 4 + elow] = (_Float16)(acc[ntl][g] + bias[ntl]);
        }
    }
    __syncthreads();
#pragma unroll
    for (int i = 0; i < 8; ++i) {
        const int c = t + 256 * i;               // 0..2047
        const int s  = c >> 6, lp = c & 63;
        const half4 hv = *(const half4*)&sm[c * 4];
        _Float16* dst = wfrag + ((((size_t)s * 9 + khw) * 4 + kbc) * 2 + oct) * 512
                              + lp * 8 + ihalf * 4;
        *(half4*)dst = hv;
    }
}

// ---------------------------------------------------------------------------
// K3: per-sample conv as implicit GEMM, mfma_f32_32x32x16_f16.
// Tile: 64 oc x 8 rows x 32 cols; 4 waves x 2 rows; 3 blocks/CU (45KB LDS).
// LDS = flat array of 16B fragment slots: slot = (xr*8 + kb*2 + h)*34 + col.
// Staging: thread owns slots tid+256*it -> linear conflict-free b128 writes;
// 8 coalesced dword loads per slot; hand-pipelined (cur/nxt).
// A-fragments double-buffered across khw.
// ---------------------------------------------------------------------------
#define XCOLS 34
#define NGRP  80                 // xr(10) * kb(4) * h(2)
#define NSLOT (NGRP * XCOLS)     // 2720
#define NIT   11                 // ceil(2720/256); pad slots up to 2816

__device__ __forceinline__ void ld_grp(const float* __restrict__ xs, int slot,
                                       int rbase, float v[8])
{
    const int grp = slot / XCOLS;
    const int col = slot - grp * XCOLS;
    const int xr  = grp >> 3;
    const int kb  = (grp >> 1) & 3;
    const int h   = grp & 1;
    const int row = min(rbase + xr, 95);
    const float* p = xs + (size_t)(kb * 16 + 4 * h) * 9216 + row * 96 + col;
#pragma unroll
    for (int c = 0; c < 4; ++c) v[c] = p[(size_t)c * 9216];
#pragma unroll
    for (int c = 0; c < 4; ++c) v[4 + c] = p[(size_t)(8 + c) * 9216];
}

__global__ __launch_bounds__(256, 3) void k3_conv(
    const float* __restrict__ x, const _Float16* __restrict__ wfrag,
    float* __restrict__ out)
{
    __shared__ __align__(16) half8 lds[NIT * 256];   // 2816 slots = 45056 B

    const int b  = blockIdx.x;
    const int wg = (b & 7) * 144 + (b >> 3);   // bijective XCD swizzle (1152%8==0)
    const int ct = wg % 3;
    const int rt = (wg / 3) % 12;
    const int s  = wg / 36;
    const int rbase  = (rt < 11) ? rt * 8 : 86;
    const int cstart = (ct == 0) ? 0 : (ct == 1) ? 32 : 62;
    const int tid = threadIdx.x;

    const float* xs = x + (size_t)s * 64 * 9216 + cstart;

    // ---- stage x tile -> LDS, software-pipelined ---------------------------
    float cur[8], nxt[8];
    ld_grp(xs, tid, rbase, cur);
#pragma unroll
    for (int it = 0; it < NIT; ++it) {
        const int slot = tid + it * 256;
        if (it + 1 < NIT) ld_grp(xs, slot + 256, rbase, nxt);
        half8 v;
#pragma unroll
        for (int c = 0; c < 8; ++c) v[c] = (_Float16)cur[c];
        lds[slot] = v;
#pragma unroll
        for (int c = 0; c < 8; ++c) cur[c] = nxt[c];
    }

    const int lane = tid & 63, wv = tid >> 6;
    const int h = lane >> 5, n31 = lane & 31;
    const int row0 = wv * 2;

    const f32x16 z16 = {0,0,0,0,0,0,0,0,0,0,0,0,0,0,0,0};
    f32x16 acc[2][2];
#pragma unroll
    for (int o = 0; o < 2; ++o)
#pragma unroll
        for (int n = 0; n < 2; ++n) acc[o][n] = z16;

    const half8* __restrict__ A = (const half8*)(wfrag + (size_t)s * WFLAT);
    half8 ac[8], an[8];
#pragma unroll
    for (int u = 0; u < 8; ++u) ac[u] = A[u * 64 + lane];   // khw = 0

    __syncthreads();

#pragma unroll
    for (int khw = 0; khw < 9; ++khw) {
        const int kh = khw / 3, kw = khw - kh * 3;
        if (khw < 8) {
#pragma unroll
            for (int u = 0; u < 8; ++u) an[u] = A[((khw + 1) * 8 + u) * 64 + lane];
        }
#pragma unroll
        for (int kb = 0; kb < 4; ++kb) {
#pragma unroll
            for (int n = 0; n < 2; ++n) {
                const int xr = row0 + n + kh;
                const half8 bb = lds[(xr * 8 + kb * 2 + h) * XCOLS + n31 + kw];
                acc[0][n] = __builtin_amdgcn_mfma_f32_32x32x16_f16(ac[kb * 2 + 0], bb, acc[0][n], 0, 0, 0);
                acc[1][n] = __builtin_amdgcn_mfma_f32_32x32x16_f16(ac[kb * 2 + 1], bb, acc[1][n], 0, 0, 0);
            }
        }
#pragma unroll
        for (int u = 0; u < 8; ++u) ac[u] = an[u];
    }

    // ---- store (C/D: col=lane&31 -> position, row=(g&3)+8*(g>>2)+4h -> oc)
    const int ocol = cstart + n31;             // always < 94
#pragma unroll
    for (int ot = 0; ot < 2; ++ot) {
#pragma unroll
        for (int n = 0; n < 2; ++n) {
            const int orow = rbase + row0 + n; // always < 94
            float* po = out + (size_t)(s * 64 + ot * 32 + 4 * h) * 8836
                            + orow * 94 + ocol;
#pragma unroll
            for (int g = 0; g < 16; ++g) {
                const int od = (g & 3) + 8 * (g >> 2);
                po[(size_t)od * 8836] = acc[ot][n][g];
            }
        }
    }
}

// ---------------------------------------------------------------------------
extern "C" void kernel_launch(void* const* d_in, const int* in_sizes, int n_in,
                              void* d_out, int out_size, void* d_ws, size_t ws_size,
                              hipStream_t stream)
{
    (void)in_sizes; (void)n_in; (void)out_size; (void)ws_size;
    const float* emb = (const float*)d_in[0];
    const float* x   = (const float*)d_in[1];
    const float* w1w = (const float*)d_in[2];
    const float* w1b = (const float*)d_in[3];
    const float* w2w = (const float*)d_in[4];
    const float* w2b = (const float*)d_in[5];
    float* out = (float*)d_out;

    _Float16* hdn16 = (_Float16*)d_ws;                        // 16 KiB
    _Float16* wfrag = (_Float16*)((char*)d_ws + 32 * 1024);   // 2.25 MiB

    k1_hdn<<<32, 256, 0, stream>>>(emb, w1w, w1b, hdn16);
    k2_wfrag<<<144, 256, 0, stream>>>(hdn16, w2w, w2b, wfrag);
    k3_conv<<<1152, 256, 0, stream>>>(x, wfrag, out);
}